// Round 14
// baseline (10607.605 us; speedup 1.0000x reference)
//
#include <hip/hip_runtime.h>
#include <stdint.h>

typedef __fp16   pkv2 __attribute__((ext_vector_type(2)));   // cvt_pkrtz result
typedef _Float16 h2   __attribute__((ext_vector_type(2)));   // fdot2 operand

// ---------------------------------------------------------------------------
// Cl(4,1) Cayley sign tables: SG float (+-1), SGN bit (1 = negative).
// ---------------------------------------------------------------------------
struct Signs { float v[32][32]; };
static constexpr Signs mk_signs() {
    Signs s{};
    for (int a = 0; a < 32; ++a)
        for (int b = 0; b < 32; ++b) {
            int c = 0;
            int t = a >> 1;
            while (t) { c ^= (__builtin_popcount(t & b) & 1); t >>= 1; }
            if (a & b & 16) c ^= 1;           // e5*e5 = -1
            s.v[a][b] = c ? -1.f : 1.f;
        }
    return s;
}
static constexpr Signs SG = mk_signs();

struct SignB { int v[32][32]; };
static constexpr SignB mk_sgn() {
    SignB s{};
    for (int a = 0; a < 32; ++a)
        for (int b = 0; b < 32; ++b)
            s.v[a][b] = (SG.v[a][b] < 0.f) ? 1 : 0;
    return s;
}
static constexpr SignB SGN = mk_sgn();

// ---- f16 pair helpers ------------------------------------------------------
__device__ __forceinline__ uint32_t pk(float a, float b) {
    union { pkv2 h; uint32_t u; } u;
    u.h = __builtin_amdgcn_cvt_pkrtz(a, b);
    return u.u;
}
__device__ __forceinline__ float dot2u(uint32_t w, uint32_t xp, float c) {
    union { uint32_t u; h2 h; } a, b; a.u = w; b.u = xp;
    return __builtin_amdgcn_fdot2(a.h, b.h, c, false);
}
__device__ __forceinline__ void unpk(uint32_t u, float& a, float& b) {
    union { uint32_t u; h2 h; } x; x.u = u;
    a = (float)x.h.x; b = (float)x.h.y;
}

// ---- DPP row-of-16 sum (VALU pipe) -----------------------------------------
template<int CTRL>
__device__ __forceinline__ float dppAdd(float v) {
    int sh = __builtin_amdgcn_update_dpp(0, __float_as_int(v), CTRL, 0xF, 0xF, true);
    return v + __int_as_float(sh);
}
__device__ __forceinline__ float rowSum16(float v) {
    v = dppAdd<0xB1>(v);    // quad_perm xor1
    v = dppAdd<0x4E>(v);    // quad_perm xor2
    v = dppAdd<0x124>(v);   // row_ror:4
    v = dppAdd<0x128>(v);   // row_ror:8
    return v;
}

// ---- packed f32 FMA with compile-time half-select / swap / sign ------------
// o.lo += (NL? -:+) d[H] * p[SW? hi:lo];  o.hi += (NH? -:+) d[H] * p[SW? lo:hi]
// (after full unroll H/SW/NL/NH are constants; branches fold to one asm each)
__device__ __forceinline__ void pkfma(float2& o, float2 d, float2 p,
                                      int H, int SW, int NL, int NH) {
#define PKA(OS, OSH, NLs, NHs)                                        \
    asm("v_pk_fma_f32 %0, %1, %2, %0 op_sel:" OS " op_sel_hi:" OSH    \
        " neg_lo:[" NLs ",0,0] neg_hi:[" NHs ",0,0]"                  \
        : "+v"(o) : "v"(d), "v"(p))
    if (H == 0 && SW == 0) {
        if      (NL == 0 && NH == 0) PKA("[0,0,0]", "[0,1,1]", "0", "0");
        else if (NL == 1 && NH == 0) PKA("[0,0,0]", "[0,1,1]", "1", "0");
        else if (NL == 0 && NH == 1) PKA("[0,0,0]", "[0,1,1]", "0", "1");
        else                         PKA("[0,0,0]", "[0,1,1]", "1", "1");
    } else if (H == 0 && SW == 1) {
        if      (NL == 0 && NH == 0) PKA("[0,1,0]", "[0,0,1]", "0", "0");
        else if (NL == 1 && NH == 0) PKA("[0,1,0]", "[0,0,1]", "1", "0");
        else if (NL == 0 && NH == 1) PKA("[0,1,0]", "[0,0,1]", "0", "1");
        else                         PKA("[0,1,0]", "[0,0,1]", "1", "1");
    } else if (H == 1 && SW == 0) {
        if      (NL == 0 && NH == 0) PKA("[1,0,0]", "[1,1,1]", "0", "0");
        else if (NL == 1 && NH == 0) PKA("[1,0,0]", "[1,1,1]", "1", "0");
        else if (NL == 0 && NH == 1) PKA("[1,0,0]", "[1,1,1]", "0", "1");
        else                         PKA("[1,0,0]", "[1,1,1]", "1", "1");
    } else {
        if      (NL == 0 && NH == 0) PKA("[1,1,0]", "[1,0,1]", "0", "0");
        else if (NL == 1 && NH == 0) PKA("[1,1,0]", "[1,0,1]", "1", "0");
        else if (NL == 0 && NH == 1) PKA("[1,1,0]", "[1,0,1]", "0", "1");
        else                         PKA("[1,1,0]", "[1,0,1]", "1", "1");
    }
#undef PKA
}

__device__ __forceinline__ void pkmul(float2& o, float2 d, float2 p, int H) {
    if (H == 0)
        asm("v_pk_mul_f32 %0, %1, %2 op_sel:[0,0] op_sel_hi:[0,1]"
            : "=v"(o) : "v"(d), "v"(p));
    else
        asm("v_pk_mul_f32 %0, %1, %2 op_sel:[1,0] op_sel_hi:[1,1]"
            : "=v"(o) : "v"(d), "v"(p));
}

// ---- packed GP: O2 = delta_H(E) (x) P2 (512 pk_fma vs 1024 scalar) ---------
// E[a] = (d1[a], d2[a]); H picks which delta. Output pair (a>>1)^m; odd a
// swaps P halves (via op_sel); Cayley signs via neg_lo/neg_hi.
__device__ __forceinline__ void gpPK(int H, const float2* __restrict__ E,
                                     const float2* __restrict__ P2,
                                     float2* __restrict__ O2) {
#pragma unroll
    for (int a = 0; a < 32; ++a) {
        const int al = a >> 1, SW = a & 1;
        if (a == 0) {
#pragma unroll
            for (int m = 0; m < 16; ++m) pkmul(O2[m], E[0], P2[m], H);
        } else {
#pragma unroll
            for (int m = 0; m < 16; ++m) {
                const int NL = SW ? SGN.v[a][2 * m + 1] : SGN.v[a][2 * m];
                const int NH = SW ? SGN.v[a][2 * m]     : SGN.v[a][2 * m + 1];
                pkfma(O2[al ^ m], E[a], P2[m], H, SW, NL, NH);
            }
        }
    }
}

// ---- scalar GP for Phase-A first pair: U2 = d2(E) (x) d1(E) ----------------
__device__ __forceinline__ void gpEE(const float2* __restrict__ E,
                                     float2* __restrict__ U2) {
#pragma unroll
    for (int a = 0; a < 32; ++a) {
        const float d = E[a].y;
        if (a == 0) {
#pragma unroll
            for (int j = 0; j < 32; ++j) {
                const float v = d * E[j].x;
                if (j & 1) U2[j >> 1].y = v; else U2[j >> 1].x = v;
            }
        } else {
#pragma unroll
            for (int j = 0; j < 32; ++j) {
                const int k = a ^ j;
                float& ref = (k & 1) ? U2[k >> 1].y : U2[k >> 1].x;
                ref = fmaf(SG.v[a][j] * d, E[j].x, ref);
            }
        }
    }
}

// ---- packed embed: E[a] = (delta1[a], delta2[a]) via 6 pk_fma --------------
__device__ __forceinline__ void embedPK(const float* __restrict__ w03h,
                                        const float4* __restrict__ wgh,
                                        const float2* __restrict__ xx,
                                        float2* __restrict__ E) {
#pragma unroll
    for (int a = 0; a < 32; ++a) {
        float4 w03 = *(const float4*)(w03h + a * 4);
        float4 w4b = wgh[a];
        const float base = w4b.z + ((a == 0) ? 1.f : 0.f);
        float2 acc = make_float2(base, base);
        float2 wA = make_float2(w03.x, w03.y);
        float2 wB = make_float2(w03.z, w03.w);
        float2 wC = make_float2(w4b.x, w4b.y);
        pkfma(acc, wA, xx[0], 0, 0, 0, 0);   // w0 broadcast
        pkfma(acc, wA, xx[1], 1, 0, 0, 0);   // w1
        pkfma(acc, wB, xx[2], 0, 0, 0, 0);   // w2
        pkfma(acc, wB, xx[3], 1, 0, 0, 0);   // w3
        pkfma(acc, wC, xx[4], 0, 0, 0, 0);   // w4
        pkfma(acc, wC, xx[5], 1, 0, 0, 0);   // w5
        E[a] = acc;
    }
}

// ---- normalize helpers -----------------------------------------------------
__device__ __forceinline__ void nrm2(float2* __restrict__ v) {
    float s0 = 0.f, s1 = 0.f, s2 = 0.f, s3 = 0.f;
#pragma unroll
    for (int m = 0; m < 16; m += 2) {
        s0 = fmaf(v[m].x, v[m].x, s0);      s1 = fmaf(v[m].y, v[m].y, s1);
        s2 = fmaf(v[m + 1].x, v[m + 1].x, s2); s3 = fmaf(v[m + 1].y, v[m + 1].y, s3);
    }
    float rs = rsqrtf((s0 + s1) + (s2 + s3) + 1e-12f);
#pragma unroll
    for (int m = 0; m < 16; ++m) { v[m].x *= rs; v[m].y *= rs; }
}
__device__ __forceinline__ void nrmF(float* __restrict__ v) {
    float s0 = 0.f, s1 = 0.f, s2 = 0.f, s3 = 0.f;
#pragma unroll
    for (int k = 0; k < 32; k += 4) {
        s0 = fmaf(v[k], v[k], s0);  s1 = fmaf(v[k + 1], v[k + 1], s1);
        s2 = fmaf(v[k + 2], v[k + 2], s2);  s3 = fmaf(v[k + 3], v[k + 3], s3);
    }
    float rs = rsqrtf((s0 + s1) + (s2 + s3) + 1e-12f);
#pragma unroll
    for (int k = 0; k < 32; ++k) v[k] *= rs;
}

// ---- Phase-B combine: R = U2 (x) unpack(f16 cell) --------------------------
__device__ __forceinline__ void scan2(const float2* __restrict__ D2v,
                                      const uint32_t* __restrict__ ps,
                                      float* __restrict__ R) {
#pragma unroll
    for (int j = 0; j < 32; ++j) R[j] = 0.f;
#pragma unroll
    for (int mq = 0; mq < 4; ++mq) {
        uint4 v = *(const uint4*)(ps + mq * 4);
        float p[8];
        unpk(v.x, p[0], p[1]); unpk(v.y, p[2], p[3]);
        unpk(v.z, p[4], p[5]); unpk(v.w, p[6], p[7]);
#pragma unroll
        for (int a = 0; a < 32; ++a) {
            const float d = (a & 1) ? D2v[a >> 1].y : D2v[a >> 1].x;
#pragma unroll
            for (int jj = 0; jj < 8; ++jj) {
                const int j = mq * 8 + jj;
                R[a ^ j] = fmaf(SG.v[a][j] * d, p[jj], R[a ^ j]);
            }
        }
    }
}

__device__ __forceinline__ void packTQ2(const float2* __restrict__ v,
                                        uint32_t* __restrict__ dst) {
#pragma unroll
    for (int mq = 0; mq < 4; ++mq)
        *(uint4*)(dst + mq * 4) =
            make_uint4(pk(v[4 * mq].x, v[4 * mq].y), pk(v[4 * mq + 1].x, v[4 * mq + 1].y),
                       pk(v[4 * mq + 2].x, v[4 * mq + 2].y), pk(v[4 * mq + 3].x, v[4 * mq + 3].y));
}
__device__ __forceinline__ void packTQf(const float* __restrict__ v,
                                        uint32_t* __restrict__ dst) {
#pragma unroll
    for (int mq = 0; mq < 4; ++mq)
        *(uint4*)(dst + mq * 4) =
            make_uint4(pk(v[8 * mq + 0], v[8 * mq + 1]), pk(v[8 * mq + 2], v[8 * mq + 3]),
                       pk(v[8 * mq + 4], v[8 * mq + 5]), pk(v[8 * mq + 6], v[8 * mq + 7]));
}

// ---- project raw P2 (f16-safe), W_out from global/L1, DPP head-reduce ------
template<int SEL>
__device__ __forceinline__ float emit2(const float2* __restrict__ P2,
                                       const uint32_t* __restrict__ woh,
                                       const float2* __restrict__ xx,
                                       const float* __restrict__ bo,
                                       int h, int b, int n, int t,
                                       float* __restrict__ out) {
    float s0 = 0.f, s1 = 0.f, s2 = 0.f, s3 = 0.f;
#pragma unroll
    for (int m = 0; m < 16; m += 2) {
        s0 = fmaf(P2[m].x, P2[m].x, s0);        s1 = fmaf(P2[m].y, P2[m].y, s1);
        s2 = fmaf(P2[m + 1].x, P2[m + 1].x, s2); s3 = fmaf(P2[m + 1].y, P2[m + 1].y, s3);
    }
    float rs = rsqrtf((s0 + s1) + (s2 + s3) + 1e-12f);
    uint32_t ph[16];
#pragma unroll
    for (int m = 0; m < 16; ++m) ph[m] = pk(P2[m].x, P2[m].y);   // raw, range-safe
    float pd[6];
#pragma unroll
    for (int dd = 0; dd < 6; ++dd) {
        uint4 w0 = *(const uint4*)(woh + dd * 16);
        uint4 w1 = *(const uint4*)(woh + dd * 16 + 4);
        uint4 w2 = *(const uint4*)(woh + dd * 16 + 8);
        uint4 w3 = *(const uint4*)(woh + dd * 16 + 12);
        float a0 = dot2u(w0.x, ph[0], 0.f);
        a0 = dot2u(w0.y, ph[1], a0);  a0 = dot2u(w0.z, ph[2], a0);
        a0 = dot2u(w0.w, ph[3], a0);  a0 = dot2u(w1.x, ph[4], a0);
        a0 = dot2u(w1.y, ph[5], a0);  a0 = dot2u(w1.z, ph[6], a0);
        a0 = dot2u(w1.w, ph[7], a0);
        float a1 = dot2u(w2.x, ph[8], 0.f);
        a1 = dot2u(w2.y, ph[9], a1);  a1 = dot2u(w2.z, ph[10], a1);
        a1 = dot2u(w2.w, ph[11], a1); a1 = dot2u(w3.x, ph[12], a1);
        a1 = dot2u(w3.y, ph[13], a1); a1 = dot2u(w3.z, ph[14], a1);
        a1 = dot2u(w3.w, ph[15], a1);
        pd[dd] = rowSum16((a0 + a1) * rs);
    }
    float v = pd[0] + (SEL ? xx[0].y : xx[0].x) + bo[0];
    v = (h == 1) ? pd[1] + (SEL ? xx[1].y : xx[1].x) + bo[1] : v;
    v = (h == 2) ? pd[2] + (SEL ? xx[2].y : xx[2].x) + bo[2] : v;
    v = (h == 3) ? pd[3] + (SEL ? xx[3].y : xx[3].x) + bo[3] : v;
    v = (h == 4) ? pd[4] + (SEL ? xx[4].y : xx[4].x) + bo[4] : v;
    v = (h == 5) ? pd[5] + (SEL ? xx[5].y : xx[5].x) + bo[5] : v;
    if (h < 6)
        out[(((size_t)b * 256 + t) * 64 + n) * 6 + h] = v;
    return rs;
}

// pair load: 12 floats for steps t, t+1 (t even) -> xx[d] = (x_t[d], x_{t+1}[d])
#define LOADXX(t, xx)                                               \
    { float4 p0 = *(const float4*)&sX[(t) * 6];                     \
      float4 p1 = *(const float4*)&sX[(t) * 6 + 4];                 \
      float4 p2 = *(const float4*)&sX[(t) * 6 + 8];                 \
      xx[0] = make_float2(p0.x, p1.z); xx[1] = make_float2(p0.y, p1.w); \
      xx[2] = make_float2(p0.z, p2.x); xx[3] = make_float2(p0.w, p2.y); \
      xx[4] = make_float2(p1.x, p2.z); xx[5] = make_float2(p1.y, p2.w); }

// ---------------------------------------------------------------------------
// Prep kernel: (w4,w5,bias,0) records + f16 W_out records in d_ws (L1/L2).
// ---------------------------------------------------------------------------
__global__ void prep(const float* __restrict__ W_in, const float* __restrict__ b_in,
                     const float* __restrict__ W_out,
                     float4* __restrict__ wsW45B, uint32_t* __restrict__ wsWo) {
    const int e = threadIdx.x;              // 512 threads
    wsW45B[e] = make_float4(W_in[2048 + e], W_in[2560 + e], b_in[e], 0.f);
    if (e < 256) {
        const int h = e >> 4, m = e & 15;
        const float* r0 = &W_out[(h * 32 + 2 * m) * 6];
#pragma unroll
        for (int dd = 0; dd < 6; ++dd)
            wsWo[h * 96 + dd * 16 + m] = pk(r0[dd], r0[6 + dd]);
    }
}

// ---------------------------------------------------------------------------
// One block per chain (b,n). 128 threads = 16 heads x 8 chunks of 32 steps.
// Round-13 structure + packed-f32 GP/embed (v_pk_fma_f32, bit-identical math).
// ---------------------------------------------------------------------------
__global__ __launch_bounds__(128, 1)
void versor(const float* __restrict__ x, const float* __restrict__ W_in,
            const float* __restrict__ b_out,
            const float4* __restrict__ wsW45B, const uint32_t* __restrict__ wsWo,
            float* __restrict__ out) {
    __shared__ __align__(16) float    sWF[16 * 132];  // [h](132): 32 blades x 4 (w0..w3)
    __shared__ __align__(16) float    sX[256 * 6];    // [t](6)
    __shared__ __align__(16) uint32_t sTQ[16 * 164];  // [h](164)[c](20): 16 f16-pairs

    const int tid = threadIdx.x;
    const int bid = blockIdx.x;
    const int chain = (bid & 7) * 128 + (bid >> 3);   // XCD-contiguous chains
    const int b = chain >> 6, n = chain & 63;

    for (int e = tid; e < 512; e += 128) {
        const int h = e >> 5, k = e & 31;
#pragma unroll
        for (int dd = 0; dd < 4; ++dd)
            sWF[h * 132 + k * 4 + dd] = W_in[dd * 512 + e];
    }
    for (int r = tid; r < 256; r += 128) {
        const float2* s2 = (const float2*)(x + (((size_t)b * 256 + r) * 64 + n) * 6);
        float2 a0 = s2[0], a1 = s2[1], a2 = s2[2];
        float* dst = &sX[r * 6];
        *(float2*)dst = a0; *(float2*)(dst + 2) = a1; *(float2*)(dst + 4) = a2;
    }

    const int h = tid & 15, c = tid >> 4;          // c in [0,8)
    float bo[6];
#pragma unroll
    for (int dd = 0; dd < 6; ++dd) bo[dd] = b_out[dd];
    __syncthreads();

    const float*    w03h = &sWF[h * 132];
    const float4*   wgh  = wsW45B + h * 32;
    const uint32_t* woh  = wsWo + h * 96;
    uint32_t*       tqh  = &sTQ[h * 164];
    const int t0 = c * 32;

    float2 U2[16], O2[16], E[32], xx[6];

    // ---- Phase A: 32-step chunk product (16 pairs, renorm every 4 pairs) ----
    LOADXX(t0, xx);
    embedPK(w03h, wgh, xx, E);
    gpEE(E, U2);                                   // psi after steps 0,1
#pragma unroll 1
    for (int q = 1; q < 16; ++q) {
        LOADXX(t0 + 2 * q, xx);
        embedPK(w03h, wgh, xx, E);
        gpPK(0, E, U2, O2);                        // O = d1 (x) U
        gpPK(1, E, O2, U2);                        // U = d2 (x) O
        if ((q & 3) == 3) nrm2(U2);                // after steps 7,15,23,31
    }
    packTQ2(U2, tqh + c * 20);
    __syncthreads();

    // ---- Phase B: Hillis-Steele inclusive scan over 8 chunks (per head) ----
#pragma unroll 1
    for (int r = 0; r < 3; ++r) {
        const int s = 1 << r;
        const bool act = (c >= s);
        float R[32];
        if (act) scan2(U2, tqh + (c - s) * 20, R); // mine (later) x earlier
        __syncthreads();
        if (act) {
            nrmF(R);
#pragma unroll
            for (int m = 0; m < 16; ++m) U2[m] = make_float2(R[2 * m], R[2 * m + 1]);
            packTQf(R, tqh + c * 20);
        }
        __syncthreads();
    }

    // ---- Phase C: replay chunk from exclusive prefix Q_c = P_{c-1} ----
    if (c == 0) {
#pragma unroll
        for (int m = 0; m < 16; ++m) U2[m] = make_float2((m == 0) ? 1.f : 0.f, 0.f);
    } else {
        const uint32_t* ps = tqh + (c - 1) * 20;
#pragma unroll
        for (int mq = 0; mq < 4; ++mq) {
            uint4 v = *(const uint4*)(ps + mq * 4);
            unpk(v.x, U2[4 * mq].x,     U2[4 * mq].y);
            unpk(v.y, U2[4 * mq + 1].x, U2[4 * mq + 1].y);
            unpk(v.z, U2[4 * mq + 2].x, U2[4 * mq + 2].y);
            unpk(v.w, U2[4 * mq + 3].x, U2[4 * mq + 3].y);
        }
    }

#pragma unroll 1
    for (int q = 0; q < 16; ++q) {
        const int t = t0 + 2 * q;
        LOADXX(t, xx);
        embedPK(w03h, wgh, xx, E);
        gpPK(0, E, U2, O2);
        emit2<0>(O2, woh, xx, bo, h, b, n, t, out);
        gpPK(1, E, O2, U2);
        float rs = emit2<1>(U2, woh, xx, bo, h, b, n, t + 1, out);
#pragma unroll
        for (int m = 0; m < 16; ++m) { U2[m].x *= rs; U2[m].y *= rs; }
    }
}

// ---------------------------------------------------------------------------
extern "C" void kernel_launch(void* const* d_in, const int* in_sizes, int n_in,
                              void* d_out, int out_size, void* d_ws, size_t ws_size,
                              hipStream_t stream) {
    const float* x     = (const float*)d_in[0];
    const float* W_in  = (const float*)d_in[1];
    const float* b_in  = (const float*)d_in[2];
    const float* W_out = (const float*)d_in[3];
    const float* b_out = (const float*)d_in[4];
    float* out = (float*)d_out;

    float4*   wsW45B = (float4*)d_ws;                    // 512 * 16B = 8 KB
    uint32_t* wsWo   = (uint32_t*)((char*)d_ws + 8192);  // 16*96*4  = 6 KB

    prep<<<1, 512, 0, stream>>>(W_in, b_in, W_out, wsW45B, wsWo);
    versor<<<1024, 128, 0, stream>>>(x, W_in, b_out, wsW45B, wsWo, out);
}

// Round 15
// 264.095 us; speedup vs baseline: 40.1658x; 40.1658x over previous
//
#include <hip/hip_runtime.h>
#include <stdint.h>

typedef __fp16   pkv2 __attribute__((ext_vector_type(2)));   // cvt_pkrtz result
typedef _Float16 h2   __attribute__((ext_vector_type(2)));   // fdot2 operand

// ---------------------------------------------------------------------------
// Cl(4,1) Cayley sign table: SG.v[a][b] = sign of e_a * e_b (blade = a ^ b).
// ---------------------------------------------------------------------------
struct Signs { float v[32][32]; };
static constexpr Signs mk_signs() {
    Signs s{};
    for (int a = 0; a < 32; ++a)
        for (int b = 0; b < 32; ++b) {
            int c = 0;
            int t = a >> 1;
            while (t) { c ^= (__builtin_popcount(t & b) & 1); t >>= 1; }
            if (a & b & 16) c ^= 1;           // e5*e5 = -1
            s.v[a][b] = c ? -1.f : 1.f;
        }
    return s;
}
static constexpr Signs SG = mk_signs();

// ---- f16 pair helpers ------------------------------------------------------
__device__ __forceinline__ uint32_t pk(float a, float b) {
    union { pkv2 h; uint32_t u; } u;
    u.h = __builtin_amdgcn_cvt_pkrtz(a, b);
    return u.u;
}
__device__ __forceinline__ float dot2u(uint32_t w, uint32_t xp, float c) {
    union { uint32_t u; h2 h; } a, b; a.u = w; b.u = xp;
    return __builtin_amdgcn_fdot2(a.h, b.h, c, false);
}
__device__ __forceinline__ void unpk(uint32_t u, float& a, float& b) {
    union { uint32_t u; h2 h; } x; x.u = u;
    a = (float)x.h.x; b = (float)x.h.y;
}

// ---- DPP row-of-16 sum (VALU pipe — keeps head-reduce off the LDS pipe) ----
template<int CTRL>
__device__ __forceinline__ float dppAdd(float v) {
    int sh = __builtin_amdgcn_update_dpp(0, __float_as_int(v), CTRL, 0xF, 0xF, true);
    return v + __int_as_float(sh);
}
__device__ __forceinline__ float rowSum16(float v) {
    v = dppAdd<0xB1>(v);    // quad_perm xor1
    v = dppAdd<0x4E>(v);    // quad_perm xor2
    v = dppAdd<0x124>(v);   // row_ror:4
    v = dppAdd<0x128>(v);   // row_ror:8
    return v;
}

// ---- paired embed: fused 32B LDS record (w0..w3 | w4,w5,bias,0) per blade --
// Loop-invariant weights live in LDS (cheap to re-issue), not global (L1
// latency exposed at 2 waves/SIMD — round 13's leak).
__device__ __forceinline__ void embedPair(const float* __restrict__ wf,
                                          float4 xv1, float2 xw1,
                                          float4 xv2, float2 xw2,
                                          float* __restrict__ D1,
                                          float* __restrict__ D2) {
#pragma unroll
    for (int a = 0; a < 32; ++a) {
        float4 w03 = *(const float4*)(wf + a * 8);
        float4 w4b = *(const float4*)(wf + a * 8 + 4);
        const float base = w4b.z + ((a == 0) ? 1.f : 0.f);
        float d1 = base, d2 = base;
        d1 = fmaf(xv1.x, w03.x, d1);  d2 = fmaf(xv2.x, w03.x, d2);
        d1 = fmaf(xv1.y, w03.y, d1);  d2 = fmaf(xv2.y, w03.y, d2);
        d1 = fmaf(xv1.z, w03.z, d1);  d2 = fmaf(xv2.z, w03.z, d2);
        d1 = fmaf(xv1.w, w03.w, d1);  d2 = fmaf(xv2.w, w03.w, d2);
        d1 = fmaf(xw1.x, w4b.x, d1);  d2 = fmaf(xw2.x, w4b.x, d2);
        d1 = fmaf(xw1.y, w4b.y, d1);  d2 = fmaf(xw2.y, w4b.y, d2);
        D1[a] = d1; D2[a] = d2;
    }
}

// ---- f32 geometric product from register operands: O = D (x) P -------------
__device__ __forceinline__ void gpF(const float* __restrict__ D,
                                    const float* __restrict__ P,
                                    float* __restrict__ O) {
#pragma unroll
    for (int a = 0; a < 32; ++a) {
        float d = D[a];
        if (a == 0) {
#pragma unroll
            for (int j = 0; j < 32; ++j) O[j] = d * P[j];
        } else {
#pragma unroll
            for (int j = 0; j < 32; ++j)
                O[a ^ j] = fmaf(SG.v[a][j] * d, P[j], O[a ^ j]);
        }
    }
}

__device__ __forceinline__ void nrmF(float* __restrict__ v) {
    float s0 = 0.f, s1 = 0.f, s2 = 0.f, s3 = 0.f;
#pragma unroll
    for (int k = 0; k < 32; k += 4) {
        s0 = fmaf(v[k], v[k], s0);  s1 = fmaf(v[k + 1], v[k + 1], s1);
        s2 = fmaf(v[k + 2], v[k + 2], s2);  s3 = fmaf(v[k + 3], v[k + 3], s3);
    }
    float rs = rsqrtf((s0 + s1) + (s2 + s3) + 1e-12f);
#pragma unroll
    for (int k = 0; k < 32; ++k) v[k] *= rs;
}

// ---- Phase-B combine: R = D (x) unpack(f16 cell) — partner streamed --------
__device__ __forceinline__ void scanR(const float* __restrict__ D,
                                      const uint32_t* __restrict__ ps,
                                      float* __restrict__ R) {
#pragma unroll
    for (int j = 0; j < 32; ++j) R[j] = 0.f;
#pragma unroll
    for (int mq = 0; mq < 4; ++mq) {
        uint4 v = *(const uint4*)(ps + mq * 4);
        float p[8];
        unpk(v.x, p[0], p[1]); unpk(v.y, p[2], p[3]);
        unpk(v.z, p[4], p[5]); unpk(v.w, p[6], p[7]);
#pragma unroll
        for (int a = 0; a < 32; ++a) {
            float d = D[a];
#pragma unroll
            for (int jj = 0; jj < 8; ++jj) {
                const int j = mq * 8 + jj;
                R[a ^ j] = fmaf(SG.v[a][j] * d, p[jj], R[a ^ j]);
            }
        }
    }
}

__device__ __forceinline__ void packTQ(const float* __restrict__ v,
                                       uint32_t* __restrict__ dst) {
#pragma unroll
    for (int mq = 0; mq < 4; ++mq)
        *(uint4*)(dst + mq * 4) =
            make_uint4(pk(v[8 * mq + 0], v[8 * mq + 1]), pk(v[8 * mq + 2], v[8 * mq + 3]),
                       pk(v[8 * mq + 4], v[8 * mq + 5]), pk(v[8 * mq + 6], v[8 * mq + 7]));
}

// ---- project raw P (f16-safe), W_out from global/L1, DPP head-reduce -------
__device__ __forceinline__ float emitOut(const float* __restrict__ P,
                                         const uint32_t* __restrict__ woh,
                                         float4 xv, float2 xw,
                                         const float* __restrict__ bo,
                                         int h, int b, int n, int t,
                                         float* __restrict__ out) {
    float s0 = 0.f, s1 = 0.f, s2 = 0.f, s3 = 0.f;
#pragma unroll
    for (int k = 0; k < 32; k += 4) {
        s0 = fmaf(P[k], P[k], s0);  s1 = fmaf(P[k + 1], P[k + 1], s1);
        s2 = fmaf(P[k + 2], P[k + 2], s2);  s3 = fmaf(P[k + 3], P[k + 3], s3);
    }
    float rs = rsqrtf((s0 + s1) + (s2 + s3) + 1e-12f);
    uint32_t ph[16];
#pragma unroll
    for (int m = 0; m < 16; ++m) ph[m] = pk(P[2 * m], P[2 * m + 1]);   // raw
    float pd[6];
#pragma unroll
    for (int dd = 0; dd < 6; ++dd) {
        uint4 w0 = *(const uint4*)(woh + dd * 16);
        uint4 w1 = *(const uint4*)(woh + dd * 16 + 4);
        uint4 w2 = *(const uint4*)(woh + dd * 16 + 8);
        uint4 w3 = *(const uint4*)(woh + dd * 16 + 12);
        float a0 = dot2u(w0.x, ph[0], 0.f);
        a0 = dot2u(w0.y, ph[1], a0);  a0 = dot2u(w0.z, ph[2], a0);
        a0 = dot2u(w0.w, ph[3], a0);  a0 = dot2u(w1.x, ph[4], a0);
        a0 = dot2u(w1.y, ph[5], a0);  a0 = dot2u(w1.z, ph[6], a0);
        a0 = dot2u(w1.w, ph[7], a0);
        float a1 = dot2u(w2.x, ph[8], 0.f);
        a1 = dot2u(w2.y, ph[9], a1);  a1 = dot2u(w2.z, ph[10], a1);
        a1 = dot2u(w2.w, ph[11], a1); a1 = dot2u(w3.x, ph[12], a1);
        a1 = dot2u(w3.y, ph[13], a1); a1 = dot2u(w3.z, ph[14], a1);
        a1 = dot2u(w3.w, ph[15], a1);
        pd[dd] = rowSum16((a0 + a1) * rs);     // DPP reduce over 16 head-lanes
    }
    float v = pd[0] + xv.x + bo[0];
    v = (h == 1) ? pd[1] + xv.y + bo[1] : v;
    v = (h == 2) ? pd[2] + xv.z + bo[2] : v;
    v = (h == 3) ? pd[3] + xv.w + bo[3] : v;
    v = (h == 4) ? pd[4] + xw.x + bo[4] : v;
    v = (h == 5) ? pd[5] + xw.y + bo[5] : v;
    if (h < 6)
        out[(((size_t)b * 256 + t) * 64 + n) * 6 + h] = v;
    return rs;
}

// pair load, chunk-padded sX (+4 floats per 32-step chunk kills the 4-way
// c-conflict: chunk base = c*196 floats -> banks spread by 4c)
#define SXBASE(t) ((t) * 6 + ((t) >> 5) * 4)
#define LOADX2(t, xv1, xw1, xv2, xw2)                               \
    { float4 p0 = *(const float4*)&sX[SXBASE(t)];                   \
      float4 p1 = *(const float4*)&sX[SXBASE(t) + 4];               \
      float4 p2 = *(const float4*)&sX[SXBASE(t) + 8];               \
      xv1 = p0; xw1 = make_float2(p1.x, p1.y);                      \
      xv2 = make_float4(p1.z, p1.w, p2.x, p2.y);                    \
      xw2 = make_float2(p2.z, p2.w); }

// ---------------------------------------------------------------------------
// Prep kernel: f16 W_out records in d_ws (6KB, L1/L2-resident for all blocks).
// ---------------------------------------------------------------------------
__global__ void prep(const float* __restrict__ W_out, uint32_t* __restrict__ wsWo) {
    const int e = threadIdx.x;              // 256 threads
    const int h = e >> 4, m = e & 15;
    const float* r0 = &W_out[(h * 32 + 2 * m) * 6];
#pragma unroll
    for (int dd = 0; dd < 6; ++dd)
        wsWo[h * 96 + dd * 16 + m] = pk(r0[dd], r0[6 + dd]);
}

// ---------------------------------------------------------------------------
// One block per chain (b,n). 128 threads = 16 heads x 8 chunks of 32 steps.
// vs round 13: loop-invariant w4/w5/bias records moved global->LDS (fused 32B
// record; LDS pipe has headroom, L1 latency at 2 waves/SIMD was the leak);
// W_out stays global; DPP head-reduce stays; sX chunk-padded.
// ---------------------------------------------------------------------------
__global__ __launch_bounds__(128, 1)
void versor(const float* __restrict__ x, const float* __restrict__ W_in,
            const float* __restrict__ b_in, const float* __restrict__ b_out,
            const uint32_t* __restrict__ wsWo, float* __restrict__ out) {
    __shared__ __align__(16) float    sWF[16 * 260];  // [h](260): 32 blades x 8
    __shared__ __align__(16) float    sX[256 * 6 + 32];  // [t](6), +4/chunk pad
    __shared__ __align__(16) uint32_t sTQ[16 * 164];  // [h](164)[c](20): 16 f16-pairs

    const int tid = threadIdx.x;
    const int bid = blockIdx.x;
    const int chain = (bid & 7) * 128 + (bid >> 3);   // XCD-contiguous chains
    const int b = chain >> 6, n = chain & 63;

    // ---- stage: fused W_in/bias records (f32) and x (f32, padded) ----
    for (int e = tid; e < 512; e += 128) {
        const int h = e >> 5, a = e & 31;
        float w0 = W_in[e], w1 = W_in[512 + e], w2 = W_in[1024 + e];
        float w3 = W_in[1536 + e], w4 = W_in[2048 + e], w5 = W_in[2560 + e];
        float bb = b_in[e];
        float* dst = &sWF[h * 260 + a * 8];
        *(float4*)dst       = make_float4(w0, w1, w2, w3);
        *(float4*)(dst + 4) = make_float4(w4, w5, bb, 0.f);
    }
    for (int r = tid; r < 256; r += 128) {
        const float2* s2 = (const float2*)(x + (((size_t)b * 256 + r) * 64 + n) * 6);
        float2 a0 = s2[0], a1 = s2[1], a2 = s2[2];
        float* dst = &sX[SXBASE(r)];
        *(float2*)dst = a0; *(float2*)(dst + 2) = a1; *(float2*)(dst + 4) = a2;
    }

    const int h = tid & 15, c = tid >> 4;          // c in [0,8)
    float bo[6];
#pragma unroll
    for (int dd = 0; dd < 6; ++dd) bo[dd] = b_out[dd];
    __syncthreads();

    const float*    wf  = &sWF[h * 260];
    const uint32_t* woh = wsWo + h * 96;
    uint32_t*       tqh = &sTQ[h * 164];
    const int t0 = c * 32;

    float U[32], O[32], D1[32], D2[32];
    float4 xv1, xv2; float2 xw1, xw2;

    // ---- Phase A: 32-step chunk product (16 pairs, renorm every 4 pairs) ----
    LOADX2(t0, xv1, xw1, xv2, xw2);
    embedPair(wf, xv1, xw1, xv2, xw2, D1, D2);
    gpF(D2, D1, U);                                // psi after steps 0,1
#pragma unroll 1
    for (int q = 1; q < 16; ++q) {
        LOADX2(t0 + 2 * q, xv1, xw1, xv2, xw2);
        embedPair(wf, xv1, xw1, xv2, xw2, D1, D2);
        gpF(D1, U, O);
        gpF(D2, O, U);
        if ((q & 3) == 3) nrmF(U);                 // after steps 7,15,23,31
    }
    packTQ(U, tqh + c * 20);
    __syncthreads();

    // ---- Phase B: Hillis-Steele inclusive scan over 8 chunks (per head) ----
#pragma unroll
    for (int j = 0; j < 32; ++j) O[j] = U[j];
#pragma unroll 1
    for (int r = 0; r < 3; ++r) {
        const int s = 1 << r;
        const bool act = (c >= s);
        float R[32];
        if (act) scanR(O, tqh + (c - s) * 20, R);  // mine (later) x earlier
        __syncthreads();
        if (act) {
            nrmF(R);
#pragma unroll
            for (int j = 0; j < 32; ++j) O[j] = R[j];
            packTQ(O, tqh + c * 20);
        }
        __syncthreads();
    }

    // ---- Phase C: replay chunk from exclusive prefix Q_c = P_{c-1} ----
    if (c == 0) {
#pragma unroll
        for (int j = 0; j < 32; ++j) U[j] = (j == 0) ? 1.f : 0.f;
    } else {
        const uint32_t* ps = tqh + (c - 1) * 20;
#pragma unroll
        for (int mq = 0; mq < 4; ++mq) {
            uint4 v = *(const uint4*)(ps + mq * 4);
            unpk(v.x, U[8 * mq + 0], U[8 * mq + 1]);
            unpk(v.y, U[8 * mq + 2], U[8 * mq + 3]);
            unpk(v.z, U[8 * mq + 4], U[8 * mq + 5]);
            unpk(v.w, U[8 * mq + 6], U[8 * mq + 7]);
        }
    }

#pragma unroll 1
    for (int q = 0; q < 16; ++q) {
        const int t = t0 + 2 * q;
        LOADX2(t, xv1, xw1, xv2, xw2);
        embedPair(wf, xv1, xw1, xv2, xw2, D1, D2);
        gpF(D1, U, O);
        emitOut(O, woh, xv1, xw1, bo, h, b, n, t, out);
        gpF(D2, O, U);
        float rs = emitOut(U, woh, xv2, xw2, bo, h, b, n, t + 1, out);
#pragma unroll
        for (int j = 0; j < 32; ++j) U[j] *= rs;   // every pair: f16-range-safe
    }
}

// ---------------------------------------------------------------------------
extern "C" void kernel_launch(void* const* d_in, const int* in_sizes, int n_in,
                              void* d_out, int out_size, void* d_ws, size_t ws_size,
                              hipStream_t stream) {
    const float* x     = (const float*)d_in[0];
    const float* W_in  = (const float*)d_in[1];
    const float* b_in  = (const float*)d_in[2];
    const float* W_out = (const float*)d_in[3];
    const float* b_out = (const float*)d_in[4];
    float* out = (float*)d_out;

    uint32_t* wsWo = (uint32_t*)d_ws;   // 16*96*4 = 6 KB, L1/L2-resident

    prep<<<1, 256, 0, stream>>>(W_out, wsWo);
    versor<<<1024, 128, 0, stream>>>(x, W_in, b_in, b_out, wsWo, out);
}